// Round 12
// baseline (240.881 us; speedup 1.0000x reference)
//
#include <hip/hip_runtime.h>
#include <hip/hip_bf16.h>

#define N_IN   200000
#define N_OUT  100000
#define NEDGE  1600000
#define CIN    64
#define KS     9
#define C_A    96
#define C_B    32
#define C_TOT  128
#define EPSV   1e-8f

#define TROWS  16            // output rows per block (MFMA M)
#define SHSTRIDE 584         // ushorts per LDS bin row: 576 + 8 pad (16B multiple)
#define KSTEPS 18            // 576 / 32
#define WPACK_ELEMS (8 * KSTEPS * 64 * 8)        // 73728 bf16

// workspace layout (bytes)
#define WS_ROWBYTES 400128                        // (N_OUT+1)*4 rounded up
#define WS_WPBYTES  147456                        // WPACK_ELEMS*2
#define WS_PERMBYTES (NEDGE * 8)                  // 12.8 MB
#define WS_FB_OFF   (WS_ROWBYTES + WS_WPBYTES + WS_PERMBYTES)
#define WS_FB_BYTES (N_IN * CIN * 2)              // 25.6 MB
#define WS_IMP_OFF  (WS_FB_OFF + WS_FB_BYTES)     // + N_OUT*4

#define BR_BLOCKS   ((NEDGE + 255) / 256)         // 6250: build_rows part
#define CAST_BLOCKS (N_IN * CIN / (256 * 8))      // 6250: feats->bf16 part
#define PREP_SORT_BLOCKS ((N_OUT + 3) / 4)        // 4 waves (rows) per 256-thr block
#define PACKW_BLOCKS ((WPACK_ELEMS + 255) / 256)  // 288

typedef __attribute__((ext_vector_type(8))) short short8;
typedef __attribute__((ext_vector_type(4))) float f32x4;

__device__ __forceinline__ unsigned short f2bf(float f) {
    __hip_bfloat16 h = __float2bfloat16(f);
    return __builtin_bit_cast(unsigned short, h);
}

// kernelA: blocks [0,BR_BLOCKS): CSR row offsets. blocks [BR_BLOCKS,...): feats->bf16.
__global__ void kernelA(const int* __restrict__ oidx, int* __restrict__ row,
                        const float* __restrict__ feats, unsigned short* __restrict__ fb) {
    if (blockIdx.x < BR_BLOCKS) {
        int e = blockIdx.x * 256 + threadIdx.x;
        if (e >= NEDGE) return;
        int cur  = oidx[e];
        int prev = (e == 0) ? -1 : oidx[e - 1];
        for (int o = prev + 1; o <= cur; ++o) row[o] = e;
        if (e == NEDGE - 1)
            for (int o = cur + 1; o <= N_OUT; ++o) row[o] = NEDGE;
    } else {
        int f = (blockIdx.x - BR_BLOCKS) * 256 + threadIdx.x;   // < 1.6M
        const float4* fp = reinterpret_cast<const float4*>(feats);
        float4 a = fp[f * 2];
        float4 b = fp[f * 2 + 1];
        short8 s;
        s[0] = (short)f2bf(a.x); s[1] = (short)f2bf(a.y);
        s[2] = (short)f2bf(a.z); s[3] = (short)f2bf(a.w);
        s[4] = (short)f2bf(b.x); s[5] = (short)f2bf(b.y);
        s[6] = (short)f2bf(b.z); s[7] = (short)f2bf(b.w);
        *reinterpret_cast<short8*>(fb + f * 8) = s;
    }
}

// prep: blocks [0,PREP_SORT_BLOCKS): one-wave-per-row ballot counting-sort by k.
// Emits perm2[e] = { nbr(18b) | k<<18 | (row&15)<<22 , bits(importance[nbr]) }
// and imp_sum[o] = per-row importance sum (moved out of the hot kernel).
// blocks [PREP_SORT_BLOCKS,...): pack W into MFMA B-frag order.
__global__ void prep_kernel(const int* __restrict__ nbr_idx,
                            const int* __restrict__ k_idx,
                            const int* __restrict__ row_start,
                            const float* __restrict__ importance,
                            const float* __restrict__ Wa,
                            const float* __restrict__ Wb,
                            uint2* __restrict__ perm2,
                            float* __restrict__ imp_sum,
                            __hip_bfloat16* __restrict__ Wp) {
    if (blockIdx.x < PREP_SORT_BLOCKS) {
        const int wave = threadIdx.x >> 6;
        const int lane = threadIdx.x & 63;
        const int o = blockIdx.x * 4 + wave;
        if (o >= N_OUT) return;
        const int e0 = row_start[o];
        const int e1 = row_start[o + 1];
        if (e0 >= e1) { if (lane == 0) imp_sum[o] = 0.f; return; }
        const unsigned hi = ((unsigned)(o & 15)) << 22;
        const unsigned long long lt = (1ULL << lane) - 1ULL;

        int basek[KS];
        #pragma unroll
        for (int j = 0; j < KS; ++j) basek[j] = 0;
        for (int base = e0; base < e1; base += 64) {
            int idx = base + lane;
            int k = (idx < e1) ? k_idx[idx] : KS;
            #pragma unroll
            for (int j = 0; j < KS; ++j)
                basek[j] += (int)__popcll(__ballot(k == j));
        }
        int run = 0;
        #pragma unroll
        for (int j = 0; j < KS; ++j) { int c = basek[j]; basek[j] = run; run += c; }
        float rsum = 0.f;
        for (int base = e0; base < e1; base += 64) {
            int idx = base + lane;
            bool valid = idx < e1;
            int k = valid ? k_idx[idx] : KS;
            unsigned nb = valid ? (unsigned)nbr_idx[idx] : 0u;
            float im = importance[nb];
            rsum += valid ? im : 0.f;
            int pos = 0;
            #pragma unroll
            for (int j = 0; j < KS; ++j) {
                unsigned long long mk = __ballot(k == j);
                if (k == j) pos = basek[j] + (int)__popcll(mk & lt);
                basek[j] += (int)__popcll(mk);
            }
            if (valid) {
                uint2 v;
                v.x = nb | hi | ((unsigned)k << 18);
                v.y = __builtin_bit_cast(unsigned, im);
                perm2[e0 + pos] = v;
            }
        }
        #pragma unroll
        for (int off = 32; off >= 1; off >>= 1) rsum += __shfl_down(rsum, off);
        if (lane == 0) imp_sum[o] = rsum;
    } else {
        int f = (blockIdx.x - PREP_SORT_BLOCKS) * 256 + threadIdx.x;
        if (f >= WPACK_ELEMS) return;
        int j = f & 7;
        int l = (f >> 3) & 63;
        int s = (f >> 9) % KSTEPS;
        int n = f / (512 * KSTEPS);
        int kc   = s * 32 + (l >> 4) * 8 + j;
        int cout = n * 16 + (l & 15);
        float v = (cout < C_A) ? Wa[kc * C_A + cout] : Wb[kc * C_B + (cout - C_A)];
        Wp[f] = __float2bfloat16(v);
    }
}

// LDS: bins 2*16*584*2 = 37376 B + imp 64 B < 40 KB => 4 blocks/CU (R11-proven).
// Phase 1 is scalar-pipe-centric: meta (perm2) values are wave-uniform ->
// readfirstlane'd into SGPRs (uniform addr should emit s_load); the gather is
// global_load_ushort with an SALU-computed scalar row base and a loop-invariant
// lane*2 voffset => ~0 per-edge VALU for addressing. Tag logic is s_cmp/branch.
// Per-edge VALU: shift-to-f32, v_add, v_fmac (iv from SGPR). Flush: cvt_pk (1).
__global__ __launch_bounds__(512, 8)
void fused_kernel(const unsigned short* __restrict__ fb,
                  const float* __restrict__ b_a,
                  const float* __restrict__ b_b,
                  const uint2* __restrict__ perm2,
                  const int* __restrict__ row_start,
                  const float* __restrict__ imp_sum,
                  const __hip_bfloat16* __restrict__ Wp,
                  float* __restrict__ out) {
    __shared__ __align__(16) unsigned short binh_a[TROWS][SHSTRIDE];
    __shared__ __align__(16) unsigned short binh_b[TROWS][SHSTRIDE];
    __shared__ float imp_s[TROWS];

    const int tid  = threadIdx.x;
    const int wave = tid >> 6;
    const int lane = tid & 63;
    const int o0   = blockIdx.x * TROWS;

    // zero bins (16B stores) + preload per-row importance sums
    {
        uint4 z = {0u, 0u, 0u, 0u};
        uint4* pa = reinterpret_cast<uint4*>(&binh_a[0][0]);
        uint4* pb = reinterpret_cast<uint4*>(&binh_b[0][0]);
        #pragma unroll
        for (int i = 0; i < 3; ++i) {
            int idx = tid + i * 512;
            if (idx < TROWS * SHSTRIDE / 8) { pa[idx] = z; pb[idx] = z; }
        }
        if (tid < TROWS) imp_s[tid] = imp_sum[o0 + tid];
    }
    __syncthreads();

    // ---- Phase 1: wave w streams the merged edge range of rows 2w, 2w+1.
    // tag = x>>18 = (lrow<<4)|k; tag-change flush covers k- and row-boundaries.
    const int lrow0 = wave * 2;
    const int E0 = __builtin_amdgcn_readfirstlane(row_start[o0 + lrow0]);
    const int E2 = __builtin_amdgcn_readfirstlane(row_start[o0 + lrow0 + 2]);

    if (E0 < E2) {
        int tagc = __builtin_amdgcn_readfirstlane((int)(perm2[E0].x >> 18));
        float acc_a = 0.f, acc_b = 0.f;

        #define FLUSH() do {                                                     \
            unsigned pk_;                                                        \
            asm("v_cvt_pk_bf16_f32 %0, %1, %2"                                   \
                : "=v"(pk_) : "v"(acc_a), "v"(acc_b));                           \
            binh_a[tagc >> 4][(tagc & 15) * CIN + lane] = (unsigned short)pk_;   \
            binh_b[tagc >> 4][(tagc & 15) * CIN + lane] = (unsigned short)(pk_ >> 16); \
            acc_a = 0.f; acc_b = 0.f; } while (0)

        for (int p = E0; p < E2; p += 8) {
            // meta batch: wave-uniform loads -> SGPRs (s_load expected)
            unsigned sx[8]; float siv[8];
            #pragma unroll
            for (int j = 0; j < 8; ++j) {
                int q = p + j; if (q >= E2) q = E2 - 1;   // clamped, scalar
                uint2 t = perm2[q];
                sx[j]  = __builtin_amdgcn_readfirstlane(t.x);
                siv[j] = __builtin_bit_cast(float, __builtin_amdgcn_readfirstlane(t.y));
            }
            // gather batch: scalar base (SALU) + invariant lane voffset
            unsigned short gh[8];
            #pragma unroll
            for (int j = 0; j < 8; ++j) {
                const unsigned short* rp = fb + (size_t)(sx[j] & 0x3FFFFu) * CIN;
                gh[j] = rp[lane];
            }
            // consume: all control scalar; 3 VALU per edge
            #pragma unroll
            for (int j = 0; j < 8; ++j) {
                if (p + j < E2) {
                    const int tag = (int)(sx[j] >> 18);
                    if (tag != tagc) { FLUSH(); tagc = tag; }
                    const float g = __builtin_bit_cast(float, (unsigned)gh[j] << 16);
                    acc_a += g;
                    acc_b = fmaf(g, siv[j], acc_b);
                }
            }
        }
        FLUSH();
        #undef FLUSH
    }
    __syncthreads();

    // ---- Phase 2: wave w computes 16x16 tile (couts w*16..w*16+15).
    // Waves 0-5 contract binh_a (C_A=96), waves 6-7 binh_b (C_B=32).
    const unsigned short* binp = (wave < 6) ? &binh_a[0][0] : &binh_b[0][0];
    const int mrow = lane & 15;   // A-fragment M index
    const int kgrp = lane >> 4;   // K-chunk select
    f32x4 acc = {0.f, 0.f, 0.f, 0.f};
    const short8* wp = reinterpret_cast<const short8*>(Wp) + wave * KSTEPS * 64 + lane;
    const unsigned short* ap0 = binp + mrow * SHSTRIDE + kgrp * 8;
    #pragma unroll
    for (int s = 0; s < KSTEPS; ++s) {
        short8 a = *reinterpret_cast<const short8*>(ap0 + s * 32);  // direct bf16 frag
        short8 b = wp[s * 64];
        acc = __builtin_amdgcn_mfma_f32_16x16x32_bf16(a, b, acc, 0, 0, 0);
    }

    // Epilogue: bias + (importance norm for B path) + relu; C/D: col=lane&15, row=kgrp*4+j
    int cout = wave * 16 + mrow;
    float bias = (wave < 6) ? b_a[cout] : b_b[cout - C_A];
    #pragma unroll
    for (int j = 0; j < 4; ++j) {
        int t = kgrp * 4 + j;
        float y = acc[j];
        if (wave >= 6) y = y / fmaxf(imp_s[t], EPSV);
        y += bias;
        y = fmaxf(y, 0.f);
        out[(long)(o0 + t) * C_TOT + cout] = y;
    }
    if (wave == 7 && lane < TROWS)
        out[(long)N_OUT * C_TOT + o0 + lane] = imp_s[lane];
}

extern "C" void kernel_launch(void* const* d_in, const int* in_sizes, int n_in,
                              void* d_out, int out_size, void* d_ws, size_t ws_size,
                              hipStream_t stream) {
    const float* feats      = (const float*)d_in[0];
    const float* importance = (const float*)d_in[1];
    const float* W_a        = (const float*)d_in[2];
    const float* b_a        = (const float*)d_in[3];
    const float* W_b        = (const float*)d_in[4];
    const float* b_b        = (const float*)d_in[5];
    const int*   nbr        = (const int*)d_in[6];
    const int*   kidx       = (const int*)d_in[7];
    const int*   oidx       = (const int*)d_in[8];
    float* out = (float*)d_out;

    int* row_start = (int*)d_ws;
    __hip_bfloat16* Wp = (__hip_bfloat16*)((char*)d_ws + WS_ROWBYTES);
    uint2* perm2 = (uint2*)((char*)d_ws + WS_ROWBYTES + WS_WPBYTES);
    unsigned short* fb = (unsigned short*)((char*)d_ws + WS_FB_OFF);
    float* imp_sum = (float*)((char*)d_ws + WS_IMP_OFF);

    hipLaunchKernelGGL(kernelA, dim3(BR_BLOCKS + CAST_BLOCKS), dim3(256), 0, stream,
                       oidx, row_start, feats, fb);
    hipLaunchKernelGGL(prep_kernel, dim3(PREP_SORT_BLOCKS + PACKW_BLOCKS), dim3(256), 0, stream,
                       nbr, kidx, row_start, importance, W_a, W_b, perm2, imp_sum, Wp);
    hipLaunchKernelGGL(fused_kernel, dim3(N_OUT / TROWS), dim3(512), 0, stream,
                       fb, b_a, b_b, perm2, row_start, imp_sum, Wp, out);
}